// Round 1
// baseline (504.191 us; speedup 1.0000x reference)
//
#include <hip/hip_runtime.h>
#include <hip/hip_bf16.h>
#include <cstdint>
#include <cstddef>

typedef __bf16 bf16_t;
typedef __bf16 bf16x8 __attribute__((ext_vector_type(8)));
typedef __bf16 bf16x4 __attribute__((ext_vector_type(4)));
typedef float  f32x4  __attribute__((ext_vector_type(4)));

#define AS1(p) ((const __attribute__((address_space(1))) unsigned int*)(p))
#define AS3(p) ((__attribute__((address_space(3))) unsigned int*)(p))

__device__ __forceinline__ float gelu_exact(float v) {
    return 0.5f * v * (1.0f + erff(v * 0.70710678118654752440f));
}

// ---------- convert W1 f32 -> bf16, same [G,D,C] layout (c inner = k inner) ----------
__global__ void k_conv_w1(const float* __restrict__ src, bf16_t* __restrict__ dst) {
    int i = blockIdx.x * 256 + threadIdx.x;   // handles 4 elements
    f32x4 v = ((const f32x4*)src)[i];
    bf16x4 o;
    o[0] = (bf16_t)v[0]; o[1] = (bf16_t)v[1];
    o[2] = (bf16_t)v[2]; o[3] = (bf16_t)v[3];
    ((bf16x4*)dst)[i] = o;
}

// ---------- x [B,C,HW] f32 -> xT [B,HW,C] bf16 (so k=c is inner for the B-operand) ----------
__global__ void k_transpose_x(const float* __restrict__ x, bf16_t* __restrict__ xT) {
    __shared__ bf16_t t[64][66];   // 66 pad: conflict-light transpose
    int bx = blockIdx.x;
    int ct = bx % 12, ht = (bx / 12) % 4, b = bx / 48;
    int tid = threadIdx.x;
    int col = tid & 63, rr = tid >> 6;   // rr in 0..3
    const float* xb = x + ((size_t)b * 768 + (size_t)ct * 64) * 256 + ht * 64;
    #pragma unroll
    for (int r = 0; r < 16; ++r) {
        int c = r * 4 + rr;
        t[c][col] = (bf16_t)xb[(size_t)c * 256 + col];   // coalesced f32 reads
    }
    __syncthreads();
    bf16_t* xTb = xT + ((size_t)b * 256 + (size_t)ht * 64) * 768 + ct * 64;
    #pragma unroll
    for (int r = 0; r < 16; ++r) {
        int hw = r * 4 + rr;
        xTb[(size_t)hw * 768 + col] = t[col][hw];        // contiguous 128B bf16 writes
    }
}

// ---------- fused grouped-GEMM + bias + exact-gelu + W2 reduction -> attn partials ----------
// block = (g, b, mt): computes h1 tile [128 rows of D][256 cols of HW], reduces over rows.
__global__ __launch_bounds__(512) void k_attn_gemm(
    const bf16_t* __restrict__ W1bf, const bf16_t* __restrict__ xTbf,
    const float* __restrict__ b1, const float* __restrict__ W2,
    float* __restrict__ attn)
{
    __shared__ bf16_t As[128 * 64];    // W1 tile [m][k], 16 KB
    __shared__ bf16_t Bs[256 * 64];    // xT tile [n][k], 32 KB
    __shared__ float  attn_s[256];

    const int tid = threadIdx.x;
    const int l = tid & 63, w = tid >> 6;
    const int wm = w >> 2, wn = w & 3;           // 2 x 4 waves, 64x64 each
    const int bx = blockIdx.x;
    const int mt = bx % 12;
    const int b  = (bx / 12) % 32;
    const int g  = bx / (12 * 32);

    const bf16_t* gA = W1bf + ((size_t)g * 1536 + (size_t)mt * 128) * 768;
    const bf16_t* gB = xTbf + (size_t)b * 256 * 768;

    if (tid < 256) attn_s[tid] = 0.0f;

    f32x4 acc[4][4];
    #pragma unroll
    for (int mi = 0; mi < 4; ++mi)
        #pragma unroll
        for (int ni = 0; ni < 4; ++ni)
            acc[mi][ni] = f32x4{0.0f, 0.0f, 0.0f, 0.0f};

    for (int kt = 0; kt < 12; ++kt) {
        const int k0 = kt * 64;
        // stage A: 128x64 bf16 = 16 KB = 2 chunks/thread (16B each)
        #pragma unroll
        for (int i = 0; i < 2; ++i) {
            int q = i * 512 + tid;               // chunk: row q>>3, cols (q&7)*8..+7
            __builtin_amdgcn_global_load_lds(
                AS1(gA + (q >> 3) * 768 + k0 + (q & 7) * 8),
                AS3((char*)As + q * 16), 16, 0, 0);
        }
        // stage B: 256x64 bf16 = 32 KB = 4 chunks/thread
        #pragma unroll
        for (int i = 0; i < 4; ++i) {
            int q = i * 512 + tid;
            __builtin_amdgcn_global_load_lds(
                AS1(gB + (q >> 3) * 768 + k0 + (q & 7) * 8),
                AS3((char*)Bs + q * 16), 16, 0, 0);
        }
        __syncthreads();   // drains vmcnt before compute
        #pragma unroll
        for (int ks = 0; ks < 2; ++ks) {
            bf16x8 af[4], bfv[4];
            #pragma unroll
            for (int mi = 0; mi < 4; ++mi) {
                int row = wm * 64 + mi * 16 + (l & 15);
                af[mi] = *(const bf16x8*)&As[row * 64 + ks * 32 + (l >> 4) * 8];
            }
            #pragma unroll
            for (int ni = 0; ni < 4; ++ni) {
                int row = wn * 64 + ni * 16 + (l & 15);
                bfv[ni] = *(const bf16x8*)&Bs[row * 64 + ks * 32 + (l >> 4) * 8];
            }
            #pragma unroll
            for (int mi = 0; mi < 4; ++mi)
                #pragma unroll
                for (int ni = 0; ni < 4; ++ni)
                    acc[mi][ni] = __builtin_amdgcn_mfma_f32_16x16x32_bf16(
                        af[mi], bfv[ni], acc[mi][ni], 0, 0, 0);
        }
        __syncthreads();   // protect single-buffered LDS
    }

    // epilogue: bias + exact gelu + W2 dot, reduce over the 128 local rows
    // C/D layout: col = l&15, row = (l>>4)*4 + reg   [m89-verified]
    float partial[4] = {0.f, 0.f, 0.f, 0.f};
    const int r0 = (l >> 4) * 4;
    #pragma unroll
    for (int mi = 0; mi < 4; ++mi) {
        int d = mt * 128 + wm * 64 + mi * 16 + r0;   // global row in D
        f32x4 b1v = *(const f32x4*)&b1[g * 1536 + d];
        f32x4 w2v = *(const f32x4*)&W2[g * 1536 + d];
        #pragma unroll
        for (int j = 0; j < 4; ++j) {
            #pragma unroll
            for (int ni = 0; ni < 4; ++ni) {
                float h = acc[mi][ni][j] + b1v[j];
                partial[ni] += gelu_exact(h) * w2v[j];
            }
        }
    }
    #pragma unroll
    for (int ni = 0; ni < 4; ++ni) {
        partial[ni] += __shfl_xor(partial[ni], 16, 64);
        partial[ni] += __shfl_xor(partial[ni], 32, 64);
    }
    if (l < 16) {
        #pragma unroll
        for (int ni = 0; ni < 4; ++ni)
            atomicAdd(&attn_s[wn * 64 + ni * 16 + l], partial[ni]);
    }
    __syncthreads();
    if (tid < 256)
        atomicAdd(&attn[((size_t)b * 8 + g) * 256 + tid], attn_s[tid]);
}

// ---------- weighted mean pool: out[b,c,g] = (1/256) sum_hw x[b,c,hw]*(attn_raw[b,g,hw]+b2[g]) ----------
__global__ void k_pool(const float* __restrict__ x, const float* __restrict__ attn,
                       const float* __restrict__ b2, float* __restrict__ out)
{
    int tid = threadIdx.x;
    int l = tid & 63, w = tid >> 6;
    int gidx = blockIdx.x * 4 + w;       // one wave per (b,c)
    int b = gidx / 768;
    f32x4 xv = ((const f32x4*)(x + (size_t)gidx * 256))[l];
    float accg[8];
    #pragma unroll
    for (int g = 0; g < 8; ++g) {
        f32x4 av = ((const f32x4*)(attn + ((size_t)b * 8 + g) * 256))[l];
        float bb = b2[g];
        accg[g] = xv[0] * (av[0] + bb) + xv[1] * (av[1] + bb)
                + xv[2] * (av[2] + bb) + xv[3] * (av[3] + bb);
    }
    #pragma unroll
    for (int g = 0; g < 8; ++g) {
        accg[g] += __shfl_xor(accg[g], 32, 64);
        accg[g] += __shfl_xor(accg[g], 16, 64);
        accg[g] += __shfl_xor(accg[g], 8, 64);
        accg[g] += __shfl_xor(accg[g], 4, 64);
        accg[g] += __shfl_xor(accg[g], 2, 64);
        accg[g] += __shfl_xor(accg[g], 1, 64);
    }
    if (l == 0) {
        #pragma unroll
        for (int g = 0; g < 8; ++g)
            out[(size_t)gidx * 8 + g] = accg[g] * (1.0f / 256.0f);
    }
}

extern "C" void kernel_launch(void* const* d_in, const int* in_sizes, int n_in,
                              void* d_out, int out_size, void* d_ws, size_t ws_size,
                              hipStream_t stream) {
    const float* x  = (const float*)d_in[0];   // [32,768,16,16]
    const float* W1 = (const float*)d_in[1];   // [8,1536,768]
    const float* b1 = (const float*)d_in[2];   // [8,1536]
    const float* W2 = (const float*)d_in[3];   // [8,1536]
    const float* b2 = (const float*)d_in[4];   // [8]
    float* out = (float*)d_out;                // [32,768,8]

    char* ws = (char*)d_ws;
    bf16_t* W1bf = (bf16_t*)ws;                              // 9437184 * 2 B
    bf16_t* xTbf = (bf16_t*)(ws + 18874368);                 // 6291456 * 2 B
    float*  attn = (float*)(ws + 18874368 + 12582912);       // 65536 * 4 B

    k_conv_w1<<<dim3(9216), dim3(256), 0, stream>>>(W1, W1bf);
    k_transpose_x<<<dim3(1536), dim3(256), 0, stream>>>(x, xTbf);
    hipMemsetAsync(attn, 0, 65536 * sizeof(float), stream);
    k_attn_gemm<<<dim3(3072), dim3(512), 0, stream>>>(W1bf, xTbf, b1, W2, attn);
    k_pool<<<dim3(6144), dim3(256), 0, stream>>>(x, attn, b2, out);
}

// Round 2
// 411.509 us; speedup vs baseline: 1.2252x; 1.2252x over previous
//
#include <hip/hip_runtime.h>
#include <hip/hip_bf16.h>
#include <cstdint>
#include <cstddef>

typedef __bf16 bf16_t;
typedef __bf16 bf16x8 __attribute__((ext_vector_type(8)));
typedef __bf16 bf16x4 __attribute__((ext_vector_type(4)));
typedef float  f32x4  __attribute__((ext_vector_type(4)));

#define AS1(p) ((const __attribute__((address_space(1))) unsigned int*)(p))
#define AS3(p) ((__attribute__((address_space(3))) unsigned int*)(p))

__device__ __forceinline__ float gelu_exact(float v) {
    return 0.5f * v * (1.0f + erff(v * 0.70710678118654752440f));
}

// ---------- convert W1 f32 -> bf16, same [G,D,C] layout (c inner = k inner) ----------
__global__ void k_conv_w1(const float* __restrict__ src, bf16_t* __restrict__ dst) {
    int i = blockIdx.x * 256 + threadIdx.x;   // handles 4 elements
    f32x4 v = ((const f32x4*)src)[i];
    bf16x4 o;
    o[0] = (bf16_t)v[0]; o[1] = (bf16_t)v[1];
    o[2] = (bf16_t)v[2]; o[3] = (bf16_t)v[3];
    ((bf16x4*)dst)[i] = o;
}

// ---------- x [B,C,HW] f32 -> xT [B,HW,C] bf16 (so k=c is inner for the B-operand) ----------
__global__ void k_transpose_x(const float* __restrict__ x, bf16_t* __restrict__ xT) {
    __shared__ bf16_t t[64][66];   // 66 pad: conflict-light transpose
    int bx = blockIdx.x;
    int ct = bx % 12, ht = (bx / 12) % 4, b = bx / 48;
    int tid = threadIdx.x;
    int col = tid & 63, rr = tid >> 6;   // rr in 0..3
    const float* xb = x + ((size_t)b * 768 + (size_t)ct * 64) * 256 + ht * 64;
    #pragma unroll
    for (int r = 0; r < 16; ++r) {
        int c = r * 4 + rr;
        t[c][col] = (bf16_t)xb[(size_t)c * 256 + col];   // coalesced f32 reads
    }
    __syncthreads();
    bf16_t* xTb = xT + ((size_t)b * 256 + (size_t)ht * 64) * 768 + ct * 64;
    #pragma unroll
    for (int r = 0; r < 16; ++r) {
        int hw = r * 4 + rr;
        xTb[(size_t)hw * 768 + col] = t[col][hw];        // contiguous 128B bf16 writes
    }
}

// ---------- fused grouped-GEMM + bias + exact-gelu + W2 reduction -> attn partials ----------
// Block mapping (XCD-aware): g = bid&7 so XCD i owns group i (W1[g]=2.25MB stays in its L2).
// Within XCD: 2-b chunks x 12 mt -> concurrent working set ~= W1[g] + 2 xT panels < 4MB.
// LDS tiles use chunk^=(row&7) XOR swizzle; global_load_lds writes linearly, so the
// SOURCE chunk index is pre-swizzled and the ds_read applies the same involution (rule #21).
__global__ __launch_bounds__(512) void k_attn_gemm(
    const bf16_t* __restrict__ W1bf, const bf16_t* __restrict__ xTbf,
    const float* __restrict__ b1, const float* __restrict__ W2,
    float* __restrict__ attn)
{
    __shared__ bf16_t As[128 * 64];    // W1 tile [m][k], 16 KB, swizzled
    __shared__ bf16_t Bs[256 * 64];    // xT tile [n][k], 32 KB, swizzled
    __shared__ float  attn_s[256];

    const int tid = threadIdx.x;
    const int l = tid & 63, w = tid >> 6;
    const int wm = w >> 2, wn = w & 3;           // 2 x 4 waves, 64x64 each
    const int bid = blockIdx.x;
    const int g     = bid & 7;                   // XCD id (round-robin heuristic)
    const int local = bid >> 3;                  // 0..383 within XCD
    const int chunk = local / 24;                // 16 chunks of 2 b's
    const int sub   = local % 24;
    const int mt    = sub >> 1;                  // 0..11
    const int b     = chunk * 2 + (sub & 1);     // 0..31

    const bf16_t* gA = W1bf + ((size_t)g * 1536 + (size_t)mt * 128) * 768;
    const bf16_t* gB = xTbf + (size_t)b * 256 * 768;

    if (tid < 256) attn_s[tid] = 0.0f;

    f32x4 acc[4][4];
    #pragma unroll
    for (int mi = 0; mi < 4; ++mi)
        #pragma unroll
        for (int ni = 0; ni < 4; ++ni)
            acc[mi][ni] = f32x4{0.0f, 0.0f, 0.0f, 0.0f};

    for (int kt = 0; kt < 12; ++kt) {
        const int k0 = kt * 64;
        // stage A: 128x64 bf16 = 16 KB = 2 chunks/thread (16B each), source pre-swizzled
        #pragma unroll
        for (int i = 0; i < 2; ++i) {
            int q = i * 512 + tid;               // phys chunk: row q>>3, slot q&7
            int row = q >> 3;
            int sc  = (q & 7) ^ (row & 7);       // logical col-chunk feeding this slot
            __builtin_amdgcn_global_load_lds(
                AS1(gA + row * 768 + k0 + sc * 8),
                AS3((char*)As + q * 16), 16, 0, 0);
        }
        // stage B: 256x64 bf16 = 32 KB = 4 chunks/thread
        #pragma unroll
        for (int i = 0; i < 4; ++i) {
            int q = i * 512 + tid;
            int row = q >> 3;
            int sc  = (q & 7) ^ (row & 7);
            __builtin_amdgcn_global_load_lds(
                AS1(gB + row * 768 + k0 + sc * 8),
                AS3((char*)Bs + q * 16), 16, 0, 0);
        }
        __syncthreads();   // drains vmcnt before compute
        #pragma unroll
        for (int ks = 0; ks < 2; ++ks) {
            const int c = ks * 4 + (l >> 4);     // logical 16B col-chunk
            bf16x8 af[4], bfv[4];
            #pragma unroll
            for (int mi = 0; mi < 4; ++mi) {
                int row = wm * 64 + mi * 16 + (l & 15);
                af[mi] = *(const bf16x8*)&As[(row * 8 + (c ^ (row & 7))) * 8];
            }
            #pragma unroll
            for (int ni = 0; ni < 4; ++ni) {
                int row = wn * 64 + ni * 16 + (l & 15);
                bfv[ni] = *(const bf16x8*)&Bs[(row * 8 + (c ^ (row & 7))) * 8];
            }
            #pragma unroll
            for (int mi = 0; mi < 4; ++mi)
                #pragma unroll
                for (int ni = 0; ni < 4; ++ni)
                    acc[mi][ni] = __builtin_amdgcn_mfma_f32_16x16x32_bf16(
                        af[mi], bfv[ni], acc[mi][ni], 0, 0, 0);
        }
        __syncthreads();   // protect single-buffered LDS
    }

    // epilogue: bias + exact gelu + W2 dot, reduce over the 128 local rows
    // C/D layout: col = l&15, row = (l>>4)*4 + reg   [m89-verified]
    float partial[4] = {0.f, 0.f, 0.f, 0.f};
    const int r0 = (l >> 4) * 4;
    #pragma unroll
    for (int mi = 0; mi < 4; ++mi) {
        int d = mt * 128 + wm * 64 + mi * 16 + r0;   // global row in D
        f32x4 b1v = *(const f32x4*)&b1[g * 1536 + d];
        f32x4 w2v = *(const f32x4*)&W2[g * 1536 + d];
        #pragma unroll
        for (int j = 0; j < 4; ++j) {
            #pragma unroll
            for (int ni = 0; ni < 4; ++ni) {
                float h = acc[mi][ni][j] + b1v[j];
                partial[ni] += gelu_exact(h) * w2v[j];
            }
        }
    }
    #pragma unroll
    for (int ni = 0; ni < 4; ++ni) {
        partial[ni] += __shfl_xor(partial[ni], 16, 64);
        partial[ni] += __shfl_xor(partial[ni], 32, 64);
    }
    if (l < 16) {
        #pragma unroll
        for (int ni = 0; ni < 4; ++ni)
            atomicAdd(&attn_s[wn * 64 + ni * 16 + l], partial[ni]);
    }
    __syncthreads();
    if (tid < 256)
        atomicAdd(&attn[((size_t)b * 8 + g) * 256 + tid], attn_s[tid]);
}

// ---------- weighted mean pool: out[b,c,g] = (1/256) sum_hw x[b,c,hw]*(attn_raw[b,g,hw]+b2[g]) ----------
__global__ void k_pool(const float* __restrict__ x, const float* __restrict__ attn,
                       const float* __restrict__ b2, float* __restrict__ out)
{
    int tid = threadIdx.x;
    int l = tid & 63, w = tid >> 6;
    int gidx = blockIdx.x * 4 + w;       // one wave per (b,c)
    int b = gidx / 768;
    f32x4 xv = ((const f32x4*)(x + (size_t)gidx * 256))[l];
    float accg[8];
    #pragma unroll
    for (int g = 0; g < 8; ++g) {
        f32x4 av = ((const f32x4*)(attn + ((size_t)b * 8 + g) * 256))[l];
        float bb = b2[g];
        accg[g] = xv[0] * (av[0] + bb) + xv[1] * (av[1] + bb)
                + xv[2] * (av[2] + bb) + xv[3] * (av[3] + bb);
    }
    #pragma unroll
    for (int g = 0; g < 8; ++g) {
        accg[g] += __shfl_xor(accg[g], 32, 64);
        accg[g] += __shfl_xor(accg[g], 16, 64);
        accg[g] += __shfl_xor(accg[g], 8, 64);
        accg[g] += __shfl_xor(accg[g], 4, 64);
        accg[g] += __shfl_xor(accg[g], 2, 64);
        accg[g] += __shfl_xor(accg[g], 1, 64);
    }
    if (l == 0) {
        #pragma unroll
        for (int g = 0; g < 8; ++g)
            out[(size_t)gidx * 8 + g] = accg[g] * (1.0f / 256.0f);
    }
}

extern "C" void kernel_launch(void* const* d_in, const int* in_sizes, int n_in,
                              void* d_out, int out_size, void* d_ws, size_t ws_size,
                              hipStream_t stream) {
    const float* x  = (const float*)d_in[0];   // [32,768,16,16]
    const float* W1 = (const float*)d_in[1];   // [8,1536,768]
    const float* b1 = (const float*)d_in[2];   // [8,1536]
    const float* W2 = (const float*)d_in[3];   // [8,1536]
    const float* b2 = (const float*)d_in[4];   // [8]
    float* out = (float*)d_out;                // [32,768,8]

    char* ws = (char*)d_ws;
    bf16_t* W1bf = (bf16_t*)ws;                              // 9437184 * 2 B
    bf16_t* xTbf = (bf16_t*)(ws + 18874368);                 // 6291456 * 2 B
    float*  attn = (float*)(ws + 18874368 + 12582912);       // 65536 * 4 B

    k_conv_w1<<<dim3(9216), dim3(256), 0, stream>>>(W1, W1bf);
    k_transpose_x<<<dim3(1536), dim3(256), 0, stream>>>(x, xTbf);
    hipMemsetAsync(attn, 0, 65536 * sizeof(float), stream);
    k_attn_gemm<<<dim3(3072), dim3(512), 0, stream>>>(W1bf, xTbf, b1, W2, attn);
    k_pool<<<dim3(6144), dim3(256), 0, stream>>>(x, attn, b2, out);
}

// Round 4
// 322.771 us; speedup vs baseline: 1.5621x; 1.2749x over previous
//
#include <hip/hip_runtime.h>
#include <hip/hip_bf16.h>
#include <cstdint>
#include <cstddef>

typedef __bf16 bf16_t;
typedef __bf16 bf16x8 __attribute__((ext_vector_type(8)));
typedef __bf16 bf16x4 __attribute__((ext_vector_type(4)));
typedef float  f32x4  __attribute__((ext_vector_type(4)));

#define AS1(p) ((const __attribute__((address_space(1))) unsigned int*)(p))
#define AS3(p) ((__attribute__((address_space(3))) unsigned int*)(p))

#if __has_builtin(__builtin_amdgcn_rcpf)
  #define FAST_RCP(x) __builtin_amdgcn_rcpf(x)
#else
  #define FAST_RCP(x) (1.0f / (x))
#endif

// Fast exact-gelu: Phi(v) via Abramowitz-Stegun 7.1.26 erf (|err| <= 1.5e-7).
// ~14 VALU vs ~40 for libm erff.
__device__ __forceinline__ float gelu_fast(float v) {
    float z = fabsf(v) * 0.70710678118654752440f;
    float t = FAST_RCP(fmaf(0.3275911f, z, 1.0f));
    float p = fmaf(t, 1.061405429f, -1.453152027f);
    p = fmaf(t, p, 1.421413741f);
    p = fmaf(t, p, -0.284496736f);
    p = fmaf(t, p, 0.254829592f);
    p *= t;
    float e = p * exp2f(-z * z * 1.4426950408889634f);   // p * exp(-z^2)
    float phi = (v >= 0.0f) ? fmaf(-0.5f, e, 1.0f) : (0.5f * e);
    return v * phi;
}

// ---------- fused prep: W1 f32->bf16 (blocks 0..9215) ; x -> xT bf16 (blocks 9216..10751) ----------
__global__ void k_prep(const float* __restrict__ W1, bf16_t* __restrict__ W1bf,
                       const float* __restrict__ x, bf16_t* __restrict__ xT) {
    __shared__ bf16_t t[64][66];
    int bx = blockIdx.x;
    int tid = threadIdx.x;
    if (bx < 9216) {
        int i = bx * 256 + tid;
        f32x4 v = ((const f32x4*)W1)[i];
        bf16x4 o;
        o[0] = (bf16_t)v[0]; o[1] = (bf16_t)v[1];
        o[2] = (bf16_t)v[2]; o[3] = (bf16_t)v[3];
        ((bf16x4*)W1bf)[i] = o;
        return;
    }
    int bx2 = bx - 9216;
    int ct = bx2 % 12, ht = (bx2 / 12) % 4, b = bx2 / 48;
    int col = tid & 63, rr = tid >> 6;
    const float* xb = x + ((size_t)b * 768 + (size_t)ct * 64) * 256 + ht * 64;
    #pragma unroll
    for (int r = 0; r < 16; ++r) {
        int c = r * 4 + rr;
        t[c][col] = (bf16_t)xb[(size_t)c * 256 + col];
    }
    __syncthreads();
    bf16_t* xTb = xT + ((size_t)b * 256 + (size_t)ht * 64) * 768 + ct * 64;
    #pragma unroll
    for (int r = 0; r < 16; ++r) {
        int hw = r * 4 + rr;
        xTb[(size_t)hw * 768 + col] = t[col][hw];
    }
}

// ---------- fused grouped-GEMM + bias + fast-gelu + W2 reduction -> attn partials ----------
// T1: g = bid&7 (one group per XCD, W1[g] L2-resident). T2: chunk^=(row&7) XOR swizzle,
// source-pre-swizzled for linear global_load_lds (rule #21). T3-min: 2-phase double-buffer,
// counted vmcnt(6) + raw s_barrier — next tile's loads stay in flight under current MFMA.
__global__ __launch_bounds__(512) void k_attn_gemm(
    const bf16_t* __restrict__ W1bf, const bf16_t* __restrict__ xTbf,
    const float* __restrict__ b1, const float* __restrict__ W2,
    float* __restrict__ attn)
{
    extern __shared__ char smem[];
    bf16_t* As0 = (bf16_t*)(smem);            // 16 KB each
    bf16_t* As1 = (bf16_t*)(smem + 16384);
    bf16_t* Bs0 = (bf16_t*)(smem + 32768);    // 32 KB each
    bf16_t* Bs1 = (bf16_t*)(smem + 65536);
    float* attn_s = (float*)(smem + 98304);   // 1 KB

    const int tid = threadIdx.x;
    const int l = tid & 63, w = tid >> 6;
    const int wm = w >> 2, wn = w & 3;           // 2 x 4 waves, 64x64 each
    const int bid = blockIdx.x;
    const int g     = bid & 7;
    const int local = bid >> 3;
    const int chunk = local / 24;
    const int sub   = local % 24;
    const int mt    = sub >> 1;
    const int b     = chunk * 2 + (sub & 1);

    const bf16_t* gA = W1bf + ((size_t)g * 1536 + (size_t)mt * 128) * 768;
    const bf16_t* gB = xTbf + (size_t)b * 256 * 768;

    if (tid < 256) attn_s[tid] = 0.0f;

    f32x4 acc[4][4];
    #pragma unroll
    for (int mi = 0; mi < 4; ++mi)
        #pragma unroll
        for (int ni = 0; ni < 4; ++ni)
            acc[mi][ni] = f32x4{0.0f, 0.0f, 0.0f, 0.0f};

    // ---- staging: 6 x 16B global_load_lds per tile (A:2, B:4), source pre-swizzled ----
    auto STAGE = [&](bf16_t* AsB, bf16_t* BsB, int k0) {
        #pragma unroll
        for (int i = 0; i < 2; ++i) {
            int q = i * 512 + tid;
            int row = q >> 3;
            int sc  = (q & 7) ^ (row & 7);
            __builtin_amdgcn_global_load_lds(AS1(gA + row * 768 + k0 + sc * 8),
                                             AS3((char*)AsB + q * 16), 16, 0, 0);
        }
        #pragma unroll
        for (int i = 0; i < 4; ++i) {
            int q = i * 512 + tid;
            int row = q >> 3;
            int sc  = (q & 7) ^ (row & 7);
            __builtin_amdgcn_global_load_lds(AS1(gB + row * 768 + k0 + sc * 8),
                                             AS3((char*)BsB + q * 16), 16, 0, 0);
        }
    };

    auto COMPUTE = [&](const bf16_t* AsB, const bf16_t* BsB) {
        #pragma unroll
        for (int ks = 0; ks < 2; ++ks) {
            const int c = ks * 4 + (l >> 4);     // logical 16B col-chunk
            bf16x8 af[4], bfv[4];
            #pragma unroll
            for (int mi = 0; mi < 4; ++mi) {
                int row = wm * 64 + mi * 16 + (l & 15);
                af[mi] = *(const bf16x8*)&AsB[(row * 8 + (c ^ (row & 7))) * 8];
            }
            #pragma unroll
            for (int ni = 0; ni < 4; ++ni) {
                int row = wn * 64 + ni * 16 + (l & 15);
                bfv[ni] = *(const bf16x8*)&BsB[(row * 8 + (c ^ (row & 7))) * 8];
            }
            #pragma unroll
            for (int mi = 0; mi < 4; ++mi)
                #pragma unroll
                for (int ni = 0; ni < 4; ++ni)
                    acc[mi][ni] = __builtin_amdgcn_mfma_f32_16x16x32_bf16(
                        af[mi], bfv[ni], acc[mi][ni], 0, 0, 0);
        }
    };

    // ---- 2-phase pipelined K-loop: 12 tiles, unrolled x2 for static buffer choice ----
    STAGE(As0, Bs0, 0);
    #pragma unroll 1
    for (int kt2 = 0; kt2 < 6; ++kt2) {
        const int kt = kt2 * 2;
        // even tile (buf0), prefetch kt+1 into buf1
        STAGE(As1, Bs1, (kt + 1) * 64);
        asm volatile("s_waitcnt vmcnt(6)" ::: "memory");   // own tile-kt loads done
        __builtin_amdgcn_s_barrier();                      // everyone's done
        COMPUTE(As0, Bs0);
        __builtin_amdgcn_s_barrier();                      // buf0 free to overwrite
        // odd tile (buf1), prefetch kt+2 into buf0
        if (kt + 2 < 12) {
            STAGE(As0, Bs0, (kt + 2) * 64);
            asm volatile("s_waitcnt vmcnt(6)" ::: "memory");
        } else {
            asm volatile("s_waitcnt vmcnt(0)" ::: "memory");
        }
        __builtin_amdgcn_s_barrier();
        COMPUTE(As1, Bs1);
        __builtin_amdgcn_s_barrier();
    }

    // ---- epilogue: bias + fast gelu + W2 dot, reduce over the 128 local rows ----
    // C/D layout: col = l&15, row = (l>>4)*4 + reg   [m89-verified]
    float partial[4] = {0.f, 0.f, 0.f, 0.f};
    const int r0 = (l >> 4) * 4;
    #pragma unroll
    for (int mi = 0; mi < 4; ++mi) {
        int d = mt * 128 + wm * 64 + mi * 16 + r0;
        f32x4 b1v = *(const f32x4*)&b1[g * 1536 + d];
        f32x4 w2v = *(const f32x4*)&W2[g * 1536 + d];
        #pragma unroll
        for (int j = 0; j < 4; ++j) {
            #pragma unroll
            for (int ni = 0; ni < 4; ++ni) {
                float h = acc[mi][ni][j] + b1v[j];
                partial[ni] += gelu_fast(h) * w2v[j];
            }
        }
    }
    #pragma unroll
    for (int ni = 0; ni < 4; ++ni) {
        partial[ni] += __shfl_xor(partial[ni], 16, 64);
        partial[ni] += __shfl_xor(partial[ni], 32, 64);
    }
    if (l < 16) {
        #pragma unroll
        for (int ni = 0; ni < 4; ++ni)
            atomicAdd(&attn_s[wn * 64 + ni * 16 + l], partial[ni]);
    }
    __syncthreads();
    if (tid < 256)
        atomicAdd(&attn[((size_t)b * 8 + g) * 256 + tid], attn_s[tid]);
}

// ---------- weighted mean pool ----------
__global__ void k_pool(const float* __restrict__ x, const float* __restrict__ attn,
                       const float* __restrict__ b2, float* __restrict__ out)
{
    int tid = threadIdx.x;
    int l = tid & 63, w = tid >> 6;
    int gidx = blockIdx.x * 4 + w;
    int b = gidx / 768;
    f32x4 xv = ((const f32x4*)(x + (size_t)gidx * 256))[l];
    float accg[8];
    #pragma unroll
    for (int g = 0; g < 8; ++g) {
        f32x4 av = ((const f32x4*)(attn + ((size_t)b * 8 + g) * 256))[l];
        float bb = b2[g];
        accg[g] = xv[0] * (av[0] + bb) + xv[1] * (av[1] + bb)
                + xv[2] * (av[2] + bb) + xv[3] * (av[3] + bb);
    }
    #pragma unroll
    for (int g = 0; g < 8; ++g) {
        accg[g] += __shfl_xor(accg[g], 32, 64);
        accg[g] += __shfl_xor(accg[g], 16, 64);
        accg[g] += __shfl_xor(accg[g], 8, 64);
        accg[g] += __shfl_xor(accg[g], 4, 64);
        accg[g] += __shfl_xor(accg[g], 2, 64);
        accg[g] += __shfl_xor(accg[g], 1, 64);
    }
    if (l == 0) {
        #pragma unroll
        for (int g = 0; g < 8; ++g)
            out[(size_t)gidx * 8 + g] = accg[g] * (1.0f / 256.0f);
    }
}

extern "C" void kernel_launch(void* const* d_in, const int* in_sizes, int n_in,
                              void* d_out, int out_size, void* d_ws, size_t ws_size,
                              hipStream_t stream) {
    const float* x  = (const float*)d_in[0];   // [32,768,16,16]
    const float* W1 = (const float*)d_in[1];   // [8,1536,768]
    const float* b1 = (const float*)d_in[2];   // [8,1536]
    const float* W2 = (const float*)d_in[3];   // [8,1536]
    const float* b2 = (const float*)d_in[4];   // [8]
    float* out = (float*)d_out;                // [32,768,8]

    char* ws = (char*)d_ws;
    bf16_t* W1bf = (bf16_t*)ws;                              // 9437184 * 2 B
    bf16_t* xTbf = (bf16_t*)(ws + 18874368);                 // 6291456 * 2 B
    float*  attn = (float*)(ws + 18874368 + 12582912);       // 65536 * 4 B

    // Unconditional every call (no static guards — harness rule); host-side, not captured.
    hipFuncSetAttribute((const void*)k_attn_gemm,
                        hipFuncAttributeMaxDynamicSharedMemorySize, 99328);

    k_prep<<<dim3(10752), dim3(256), 0, stream>>>(W1, W1bf, x, xTbf);
    hipMemsetAsync(attn, 0, 65536 * sizeof(float), stream);
    k_attn_gemm<<<dim3(3072), dim3(512), 99328, stream>>>(W1bf, xTbf, b1, W2, attn);
    k_pool<<<dim3(6144), dim3(256), 0, stream>>>(x, attn, b2, out);
}

// Round 7
// 317.004 us; speedup vs baseline: 1.5905x; 1.0182x over previous
//
#include <hip/hip_runtime.h>
#include <hip/hip_bf16.h>
#include <cstdint>
#include <cstddef>

typedef __bf16 bf16_t;
typedef __bf16 bf16x8 __attribute__((ext_vector_type(8)));
typedef __bf16 bf16x4 __attribute__((ext_vector_type(4)));
typedef float  f32x4  __attribute__((ext_vector_type(4)));
typedef float  f32x16 __attribute__((ext_vector_type(16)));

#define AS1(p) ((const __attribute__((address_space(1))) unsigned int*)(p))
#define AS3(p) ((__attribute__((address_space(3))) unsigned int*)(p))

#if __has_builtin(__builtin_amdgcn_rcpf)
  #define FAST_RCP(x) __builtin_amdgcn_rcpf(x)
#else
  #define FAST_RCP(x) (1.0f / (x))
#endif

// Fast exact-gelu: Phi(v) via Abramowitz-Stegun 7.1.26 erf (|err| <= 1.5e-7).
__device__ __forceinline__ float gelu_fast(float v) {
    float z = fabsf(v) * 0.70710678118654752440f;
    float t = FAST_RCP(fmaf(0.3275911f, z, 1.0f));
    float p = fmaf(t, 1.061405429f, -1.453152027f);
    p = fmaf(t, p, 1.421413741f);
    p = fmaf(t, p, -0.284496736f);
    p = fmaf(t, p, 0.254829592f);
    p *= t;
    float e = p * exp2f(-z * z * 1.4426950408889634f);
    float phi = (v >= 0.0f) ? fmaf(-0.5f, e, 1.0f) : (0.5f * e);
    return v * phi;
}

// ---------- fused prep: W1 f32->bf16 | x -> xT bf16 | attn zero-init ----------
__global__ void k_prep(const float* __restrict__ W1, bf16_t* __restrict__ W1bf,
                       const float* __restrict__ x, bf16_t* __restrict__ xT,
                       float* __restrict__ attn) {
    __shared__ bf16_t t[64][66];
    int bx = blockIdx.x;
    int tid = threadIdx.x;
    if (bx < 9216) {
        int i = bx * 256 + tid;
        f32x4 v = ((const f32x4*)W1)[i];
        bf16x4 o;
        o[0] = (bf16_t)v[0]; o[1] = (bf16_t)v[1];
        o[2] = (bf16_t)v[2]; o[3] = (bf16_t)v[3];
        ((bf16x4*)W1bf)[i] = o;
        return;
    }
    if (bx >= 10752) {   // 64 blocks zero attn (65536 f32)
        int i = (bx - 10752) * 256 + tid;
        ((f32x4*)attn)[i] = f32x4{0.f, 0.f, 0.f, 0.f};
        return;
    }
    int bx2 = bx - 9216;
    int ct = bx2 % 12, ht = (bx2 / 12) % 4, b = bx2 / 48;
    int col = tid & 63, rr = tid >> 6;
    const float* xb = x + ((size_t)b * 768 + (size_t)ct * 64) * 256 + ht * 64;
    #pragma unroll
    for (int r = 0; r < 16; ++r) {
        int c = r * 4 + rr;
        t[c][col] = (bf16_t)xb[(size_t)c * 256 + col];
    }
    __syncthreads();
    bf16_t* xTb = xT + ((size_t)b * 256 + (size_t)ht * 64) * 768 + ct * 64;
    #pragma unroll
    for (int r = 0; r < 16; ++r) {
        int hw = r * 4 + rr;
        xTb[(size_t)hw * 768 + col] = t[col][hw];
    }
}

// ---------- fused grouped-GEMM + bias + fast-gelu + W2 reduction -> attn partials ----------
// T1: g = bid&7 (group per XCD). T2: chunk^(row&7) swizzle, source-pre-swizzled.
// T3-min: 2-phase dbuf, counted vmcnt(6). 32x32x16 MFMA + hoisted K-loop addresses.
// R7 fix: boff[][] is now RELATIVE to the B-buffer base (the Bs0 base had been baked
// in AND added again via bbase -> OOB LDS reads -> NaN).
__global__ __launch_bounds__(512) void k_attn_gemm(
    const bf16_t* __restrict__ W1bf, const bf16_t* __restrict__ xTbf,
    const float* __restrict__ b1, const float* __restrict__ W2,
    float* __restrict__ attn)
{
    extern __shared__ char smem[];
    // layout: As0 @0 (16K) | As1 @16384 | Bs0 @32768 (32K) | Bs1 @65536 | attn_s @98304
    float* attn_s = (float*)(smem + 98304);

    const int tid = threadIdx.x;
    const int l = tid & 63, w = tid >> 6;
    const int wm = w >> 2, wn = w & 3;           // 2 x 4 waves, 64x64 tile each
    const int bid = blockIdx.x;
    const int g     = bid & 7;
    const int local = bid >> 3;
    const int chunk = local / 24;
    const int sub   = local % 24;
    const int mt    = sub >> 1;
    const int b     = chunk * 2 + (sub & 1);

    const bf16_t* gAk = W1bf + ((size_t)g * 1536 + (size_t)mt * 128) * 768;
    const bf16_t* gBk = xTbf + (size_t)b * 256 * 768;

    if (tid < 256) attn_s[tid] = 0.0f;

    // ---- hoisted staging offsets (per-lane, kt-invariant) ----
    int voffA[2], ldsA[2], voffB[4], ldsB[4];
    #pragma unroll
    for (int i = 0; i < 2; ++i) {
        int q = i * 512 + tid, row = q >> 3, sc = (q & 7) ^ (row & 7);
        voffA[i] = row * 768 + sc * 8;
        ldsA[i] = q * 16;
    }
    #pragma unroll
    for (int i = 0; i < 4; ++i) {
        int q = i * 512 + tid, row = q >> 3, sc = (q & 7) ^ (row & 7);
        voffB[i] = row * 768 + sc * 8;
        ldsB[i] = q * 16;
    }

    // ---- hoisted LDS read offsets (kt-invariant, buffer-RELATIVE; base via arg) ----
    // A/B frag: row = l&31 within 32-block, k-chunk = l>>5 within K=16 slice.
    const int hi = l >> 5;
    uint32_t aoff[4][2], boff[4][2];
    #pragma unroll
    for (int ks = 0; ks < 4; ++ks) {
        const int c = ks * 2 + hi;
        #pragma unroll
        for (int mi = 0; mi < 2; ++mi) {
            int r = wm * 64 + mi * 32 + (l & 31);
            aoff[ks][mi] = (uint32_t)((r * 8 + (c ^ (r & 7))) * 16);
        }
        #pragma unroll
        for (int ni = 0; ni < 2; ++ni) {
            int r = wn * 64 + ni * 32 + (l & 31);
            boff[ks][ni] = (uint32_t)((r * 8 + (c ^ (r & 7))) * 16);   // RELATIVE (fix)
        }
    }

    f32x16 acc[2][2];
    #pragma unroll
    for (int mi = 0; mi < 2; ++mi)
        #pragma unroll
        for (int ni = 0; ni < 2; ++ni)
            acc[mi][ni] = (f32x16)(0.0f);

    auto STAGE = [&](int abase, int bbase) {
        #pragma unroll
        for (int i = 0; i < 2; ++i)
            __builtin_amdgcn_global_load_lds(AS1(gAk + voffA[i]),
                AS3(smem + abase + ldsA[i]), 16, 0, 0);
        #pragma unroll
        for (int i = 0; i < 4; ++i)
            __builtin_amdgcn_global_load_lds(AS1(gBk + voffB[i]),
                AS3(smem + bbase + ldsB[i]), 16, 0, 0);
        gAk += 64; gBk += 64;   // uniform base walk (SALU)
    };

    auto COMPUTE = [&](int abase, int bbase) {
        #pragma unroll
        for (int ks = 0; ks < 4; ++ks) {
            bf16x8 af[2], bfr[2];
            #pragma unroll
            for (int mi = 0; mi < 2; ++mi)
                af[mi] = *(const bf16x8*)(smem + abase + aoff[ks][mi]);
            #pragma unroll
            for (int ni = 0; ni < 2; ++ni)
                bfr[ni] = *(const bf16x8*)(smem + bbase + boff[ks][ni]);
            #pragma unroll
            for (int mi = 0; mi < 2; ++mi)
                #pragma unroll
                for (int ni = 0; ni < 2; ++ni)
                    acc[mi][ni] = __builtin_amdgcn_mfma_f32_32x32x16_bf16(
                        af[mi], bfr[ni], acc[mi][ni], 0, 0, 0);
        }
    };

    // ---- 2-phase pipelined K-loop: 12 tiles ----
    STAGE(0, 32768);                       // tile 0 -> buf0
    #pragma unroll 1
    for (int kt2 = 0; kt2 < 5; ++kt2) {
        STAGE(16384, 65536);               // odd tile -> buf1
        asm volatile("s_waitcnt vmcnt(6)" ::: "memory");
        __builtin_amdgcn_s_barrier();
        COMPUTE(0, 32768);
        __builtin_amdgcn_s_barrier();
        STAGE(0, 32768);                   // even tile -> buf0
        asm volatile("s_waitcnt vmcnt(6)" ::: "memory");
        __builtin_amdgcn_s_barrier();
        COMPUTE(16384, 65536);
        __builtin_amdgcn_s_barrier();
    }
    STAGE(16384, 65536);                   // tile 11 -> buf1
    asm volatile("s_waitcnt vmcnt(6)" ::: "memory");
    __builtin_amdgcn_s_barrier();
    COMPUTE(0, 32768);                     // tile 10
    asm volatile("s_waitcnt vmcnt(0)" ::: "memory");
    __builtin_amdgcn_s_barrier();
    COMPUTE(16384, 65536);                 // tile 11

    // ---- epilogue: bias + gelu + W2 dot over the 128 local D-rows ----
    // 32x32 C/D: col = l&31, row = (rg&3) + 8*(rg>>2) + 4*(l>>5)  [m74/m101]
    float partial[2] = {0.f, 0.f};
    #pragma unroll
    for (int mi = 0; mi < 2; ++mi) {
        const int dbase = g * 1536 + mt * 128 + wm * 64 + mi * 32 + hi * 4;
        #pragma unroll
        for (int rq = 0; rq < 4; ++rq) {
            f32x4 b1v = *(const f32x4*)&b1[dbase + rq * 8];
            f32x4 w2v = *(const f32x4*)&W2[dbase + rq * 8];
            #pragma unroll
            for (int j = 0; j < 4; ++j) {
                const int rg = rq * 4 + j;
                #pragma unroll
                for (int ni = 0; ni < 2; ++ni) {
                    float h = acc[mi][ni][rg] + b1v[j];
                    partial[ni] += gelu_fast(h) * w2v[j];
                }
            }
        }
    }
    #pragma unroll
    for (int ni = 0; ni < 2; ++ni)
        partial[ni] += __shfl_xor(partial[ni], 32, 64);
    if (l < 32) {
        #pragma unroll
        for (int ni = 0; ni < 2; ++ni)
            atomicAdd(&attn_s[wn * 64 + ni * 32 + l], partial[ni]);
    }
    __syncthreads();
    if (tid < 256)
        atomicAdd(&attn[((size_t)b * 8 + g) * 256 + tid], attn_s[tid]);
}

// ---------- weighted mean pool ----------
__global__ void k_pool(const float* __restrict__ x, const float* __restrict__ attn,
                       const float* __restrict__ b2, float* __restrict__ out)
{
    int tid = threadIdx.x;
    int l = tid & 63, w = tid >> 6;
    int gidx = blockIdx.x * 4 + w;
    int b = gidx / 768;
    f32x4 xv = ((const f32x4*)(x + (size_t)gidx * 256))[l];
    float accg[8];
    #pragma unroll
    for (int g = 0; g < 8; ++g) {
        f32x4 av = ((const f32x4*)(attn + ((size_t)b * 8 + g) * 256))[l];
        float bb = b2[g];
        accg[g] = xv[0] * (av[0] + bb) + xv[1] * (av[1] + bb)
                + xv[2] * (av[2] + bb) + xv[3] * (av[3] + bb);
    }
    #pragma unroll
    for (int g = 0; g < 8; ++g) {
        accg[g] += __shfl_xor(accg[g], 32, 64);
        accg[g] += __shfl_xor(accg[g], 16, 64);
        accg[g] += __shfl_xor(accg[g], 8, 64);
        accg[g] += __shfl_xor(accg[g], 4, 64);
        accg[g] += __shfl_xor(accg[g], 2, 64);
        accg[g] += __shfl_xor(accg[g], 1, 64);
    }
    if (l == 0) {
        #pragma unroll
        for (int g = 0; g < 8; ++g)
            out[(size_t)gidx * 8 + g] = accg[g] * (1.0f / 256.0f);
    }
}

extern "C" void kernel_launch(void* const* d_in, const int* in_sizes, int n_in,
                              void* d_out, int out_size, void* d_ws, size_t ws_size,
                              hipStream_t stream) {
    const float* x  = (const float*)d_in[0];   // [32,768,16,16]
    const float* W1 = (const float*)d_in[1];   // [8,1536,768]
    const float* b1 = (const float*)d_in[2];   // [8,1536]
    const float* W2 = (const float*)d_in[3];   // [8,1536]
    const float* b2 = (const float*)d_in[4];   // [8]
    float* out = (float*)d_out;                // [32,768,8]

    char* ws = (char*)d_ws;
    bf16_t* W1bf = (bf16_t*)ws;                              // 9437184 * 2 B
    bf16_t* xTbf = (bf16_t*)(ws + 18874368);                 // 6291456 * 2 B
    float*  attn = (float*)(ws + 18874368 + 12582912);       // 65536 * 4 B

    hipFuncSetAttribute((const void*)k_attn_gemm,
                        hipFuncAttributeMaxDynamicSharedMemorySize, 99328);

    k_prep<<<dim3(10816), dim3(256), 0, stream>>>(W1, W1bf, x, xTbf, attn);
    k_attn_gemm<<<dim3(3072), dim3(512), 99328, stream>>>(W1bf, xTbf, b1, W2, attn);
    k_pool<<<dim3(6144), dim3(256), 0, stream>>>(x, attn, b2, out);
}